// Round 14
// baseline (523.570 us; speedup 1.0000x reference)
//
#include <hip/hip_runtime.h>
#include <hip/hip_bf16.h>

// GAT: N=50000 nodes, E=800000 edges, L=3 layers, H=8 heads, C=16, F=128.
// flags[0]=1 -> float tensors fp32 (else bf16); flags[1]=1 -> edge_index int64.
// R14: fix R13's fused-FC register-pressure bug. R13 held 32 fc_w VGPRs live
// ACROSS the edge loop -> compiler serialized the 8-gather unroll (VALUBusy
// 38->17%, same FETCH, 2x time). Now fc_w rows load AFTER the loop; a
// loop-result-dependent address guard (lsum>0, always true) defeats LICM
// hoisting. Main loop register budget back to plain-aggregate levels.

#define GAT_F 128
#define GAT_H 8
#define GAT_C 16

typedef __attribute__((ext_vector_type(8))) short bf16x8;
typedef __attribute__((ext_vector_type(4))) float f32x4;

__device__ __forceinline__ float bf2f(unsigned short u) {
    union { unsigned int i; float f; } x; x.i = ((unsigned int)u) << 16; return x.f;
}
__device__ __forceinline__ float bfhi2f(unsigned int u) {
    union { unsigned int i; float f; } x; x.i = u & 0xFFFF0000u; return x.f;
}
__device__ __forceinline__ float bflo2f(unsigned int u) {
    union { unsigned int i; float f; } x; x.i = u << 16; return x.f;
}
__device__ __forceinline__ unsigned int pk_bf16(float a, float b) {  // rne pack
    union { float f; unsigned int i; } ua, ub;
    ua.f = a; ub.f = b;
    unsigned int ra = (ua.i + 0x7FFFu + ((ua.i >> 16) & 1u)) >> 16;
    unsigned int rb = (ub.i + 0x7FFFu + ((ub.i >> 16) & 1u)) & 0xFFFF0000u;
    return ra | rb;
}
__device__ __forceinline__ unsigned short f2bf(float a) {
    union { float f; unsigned int i; } ua; ua.f = a;
    return (unsigned short)((ua.i + 0x7FFFu + ((ua.i >> 16) & 1u)) >> 16);
}
__device__ __forceinline__ float ldf(const void* p, size_t i, int isf32) {
    return isf32 ? ((const float*)p)[i] : bf2f(((const unsigned short*)p)[i]);
}
__device__ __forceinline__ int ldei(const int* ei, int i, int is64) {
    return is64 ? ei[2 * (size_t)i] : ei[i];
}

// ---------- fused: dtype detection (last block) + init_deg (others) ----------
__global__ void k_detect_init(const unsigned short* __restrict__ xb,
                              const int* __restrict__ ei, int* flags,
                              int* deg, int n, int nb_n) {
    if ((int)blockIdx.x < nb_n) {
        int i = blockIdx.x * 256 + threadIdx.x;
        if (i < n) deg[i] = 1;  // self loop
        return;
    }
    __shared__ int nan_cnt, zero_cnt;
    if (threadIdx.x == 0) { nan_cnt = 0; zero_cnt = 0; }
    __syncthreads();
    int t = threadIdx.x;
    int ln = 0;
    for (int i = t; i < 8192; i += 256) {
        unsigned short u = xb[i];
        if ((u & 0x7F80) == 0x7F80) ln++;   // bf16 inf/nan pattern
    }
    int lz = 0;
    for (int i = t; i < 2048; i += 256) {
        if (ei[2 * i + 1] == 0) lz++;       // int64 high words all zero
    }
    if (ln) atomicAdd(&nan_cnt, ln);
    if (lz) atomicAdd(&zero_cnt, lz);
    __syncthreads();
    if (t == 0) {
        flags[0] = (nan_cnt > 3) ? 1 : 0;
        flags[1] = (zero_cnt > 1024) ? 1 : 0;
    }
}

// ---------- fused: prep (first Lw*72 blocks) + count_deg (rest) ----------
__global__ void k_prep_count(const void* __restrict__ W, const void* __restrict__ asrc,
                             const void* __restrict__ adst,
                             unsigned short* __restrict__ wt, unsigned short* __restrict__ wa,
                             int Lw, const int* __restrict__ ei, int* deg, int E,
                             const int* __restrict__ flags) {
    int isf32 = flags[0];
    int b = blockIdx.x, t = threadIdx.x;
    if (b < Lw * 64) {
        int gid = b * 256 + t;                 // over L*16384
        int l = gid >> 14, r = gid & 16383;
        int c = r >> 7, k = r & 127;
        float v = ldf(W, (size_t)l * 16384 + k * 128 + c, isf32);
        wt[gid] = f2bf(v);                     // wt layout: l*16384 + c*128 + k
    } else if (b < Lw * 72) {
        int id = (b - Lw * 64) * 256 + t;      // over L*2048
        int l = id >> 11, q = id & 2047;
        int j = q >> 7, k = q & 127;
        int head = j & 7;
        const void* av = (j < 8) ? asrc : adst;
        float acc = 0.f;
        #pragma unroll
        for (int cc = 0; cc < 16; cc++) {
            float w = ldf(W, (size_t)l * 16384 + k * 128 + head * 16 + cc, isf32);
            float a = ldf(av, (size_t)l * 128 + head * 16 + cc, isf32);
            acc += w * a;
        }
        wa[id] = f2bf(acc);                    // wa layout: l*2048 + j*128 + k
    } else {
        int k = (b - Lw * 72) * 256 + t;
        int is64 = flags[1];
        if (k < E) atomicAdd(&deg[ldei(ei, E + k, is64)], 1);
    }
}

__global__ __launch_bounds__(256) void k_scan_blk(
    const int* __restrict__ deg, int* __restrict__ rp_local,
    int* __restrict__ bsum, int n)
{
    int b = blockIdx.x, t = threadIdx.x;
    int i0 = b * 1024 + t * 4;
    int v0 = 0, v1 = 0, v2 = 0, v3 = 0;
    if (i0 + 3 < n) {
        int4 d = *(const int4*)(deg + i0);
        v0 = d.x; v1 = d.y; v2 = d.z; v3 = d.w;
    } else {
        if (i0     < n) v0 = deg[i0];
        if (i0 + 1 < n) v1 = deg[i0 + 1];
        if (i0 + 2 < n) v2 = deg[i0 + 2];
        if (i0 + 3 < n) v3 = deg[i0 + 3];
    }
    int s = v0 + v1 + v2 + v3;
    int lane = t & 63, wid = t >> 6;
    int sc = s;
    #pragma unroll
    for (int off = 1; off < 64; off <<= 1) {
        int o = __shfl_up(sc, off);
        if (lane >= off) sc += o;
    }
    __shared__ int wsum[4];
    if (lane == 63) wsum[wid] = sc;
    __syncthreads();
    int woff = 0;
    #pragma unroll
    for (int w2 = 0; w2 < 4; w2++) if (w2 < wid) woff += wsum[w2];
    int excl = woff + sc - s;
    if (i0     < n) rp_local[i0]     = excl;
    if (i0 + 1 < n) rp_local[i0 + 1] = excl + v0;
    if (i0 + 2 < n) rp_local[i0 + 2] = excl + v0 + v1;
    if (i0 + 3 < n) rp_local[i0 + 3] = excl + v0 + v1 + v2;
    if (t == 255) bsum[b] = woff + sc;
}

// place_add with inline scan of bsum (raw per-block totals; nb_s <= 1024)
__global__ void k_place_add(int* __restrict__ rowptr, const int* __restrict__ bsum,
                            int* __restrict__ adj, int* __restrict__ cursor,
                            int n, int nb_s)
{
    int i = blockIdx.x * 256 + threadIdx.x;
    if (i < n) {
        int myblk = i >> 10;
        int off = 0;
        for (int b = 0; b < myblk; b++) off += bsum[b];   // <=48 L1-hot loads
        int r = rowptr[i] + off;
        rowptr[i] = r;
        adj[r] = i;
        cursor[i] = 1;
    }
    if (blockIdx.x == 0 && threadIdx.x < 9) {
        int tot = 0;
        for (int b = 0; b < nb_s; b++) tot += bsum[b];
        if (threadIdx.x == 0) rowptr[n] = tot;
        else adj[tot + threadIdx.x - 1] = 0;   // pad 8 slots for agg unroll overread
    }
}

// ---------- fused: gemm layer 0 (blocks < nb_g) + scatter (rest) ----------
__global__ __launch_bounds__(256) void k_gemm_scatter(
    const void* __restrict__ xin,
    const unsigned short* __restrict__ wt, const unsigned short* __restrict__ wa,
    unsigned int* __restrict__ hb, float* __restrict__ es, float* __restrict__ ed,
    int n, int nb_g,
    const int* __restrict__ ei, const int* __restrict__ rowptr,
    int* __restrict__ cursor, int* __restrict__ adj, int E,
    const int* __restrict__ flags)
{
    __shared__ unsigned short xl[64 * 136];
    int isf32 = flags[0];
    int t = threadIdx.x;

    if ((int)blockIdx.x >= nb_g) {   // ---- scatter blocks ----
        int k = ((int)blockIdx.x - nb_g) * 256 + t;
        int is64 = flags[1];
        if (k < E) {
            int s = ldei(ei, k, is64);
            int d = ldei(ei, E + k, is64);
            int p = atomicAdd(&cursor[d], 1);
            adj[rowptr[d] + p] = s;
        }
        return;
    }

    // ---- gemm layer 0 (x_is_input) ----
    int row0 = blockIdx.x * 64;
    int lane = t & 63, wid = t >> 6, quad = lane >> 4, col = lane & 15;

    bool direct = !isf32;   // bf16 input tensor -> read fragments from global
    if (!direct) {
        const float4* xg = (const float4*)xin;
        for (int i = t; i < 2048; i += 256) {
            int r = i >> 5, c4 = i & 31;
            int gr = row0 + r;
            uint2 u = make_uint2(0u, 0u);
            if (gr < n) {
                float4 v = xg[(size_t)gr * 32 + c4];
                u = make_uint2(pk_bf16(v.x, v.y), pk_bf16(v.z, v.w));
            }
            *(uint2*)&xl[r * 136 + c4 * 4] = u;
        }
        __syncthreads();
    }

    int arow = row0 + wid * 16 + col;
    int arowc = min(arow, n - 1);
    const unsigned short* xrow = direct
        ? ((const unsigned short*)xin + (size_t)arowc * 128)
        : &xl[(wid * 16 + col) * 136];

    f32x4 acc[9];
    #pragma unroll
    for (int ct = 0; ct < 9; ct++) acc[ct] = (f32x4){0.f, 0.f, 0.f, 0.f};

    #pragma unroll
    for (int ks = 0; ks < 4; ks++) {
        int k0 = ks * 32;
        bf16x8 af = *(const bf16x8*)&xrow[k0 + quad * 8];
        #pragma unroll
        for (int ct = 0; ct < 9; ct++) {
            const unsigned short* bsrc = (ct < 8) ? &wt[(ct * 16 + col) * 128]
                                                  : &wa[col * 128];
            bf16x8 bf = *(const bf16x8*)&bsrc[k0 + quad * 8];
            acc[ct] = __builtin_amdgcn_mfma_f32_16x16x32_bf16(af, bf, acc[ct], 0, 0, 0);
        }
    }

    #pragma unroll
    for (int ct = 0; ct < 8; ct++) {
        #pragma unroll
        for (int r = 0; r < 4; r++) {
            int grow = row0 + wid * 16 + quad * 4 + r;
            float v = acc[ct][r];
            float vp = __shfl_xor(v, 1);
            if (!(lane & 1) && grow < n)
                hb[(size_t)grow * 64 + ct * 8 + (col >> 1)] = pk_bf16(v, vp);
        }
    }
    #pragma unroll
    for (int r = 0; r < 4; r++) {
        int grow = row0 + wid * 16 + quad * 4 + r;
        float v = acc[8][r];
        if (grow < n) {
            if (col < 8) es[(size_t)grow * 8 + col] = v;
            else         ed[(size_t)grow * 8 + col - 8] = v;
        }
    }
}

// ---------- MFMA GEMM (layers 1..L-1, packed-bf16 input) ----------
__global__ __launch_bounds__(256) void k_gemm_mfma(
    const void* __restrict__ xin,
    const unsigned short* __restrict__ wt, const unsigned short* __restrict__ wa,
    unsigned int* __restrict__ hb, float* __restrict__ es, float* __restrict__ ed,
    int n, const int* __restrict__ flags)
{
    int t = threadIdx.x;
    int row0 = blockIdx.x * 64;
    int lane = t & 63, wid = t >> 6, quad = lane >> 4, col = lane & 15;

    int arow = row0 + wid * 16 + col;
    int arowc = min(arow, n - 1);
    const unsigned short* xrow = (const unsigned short*)xin + (size_t)arowc * 128;

    f32x4 acc[9];
    #pragma unroll
    for (int ct = 0; ct < 9; ct++) acc[ct] = (f32x4){0.f, 0.f, 0.f, 0.f};

    #pragma unroll
    for (int ks = 0; ks < 4; ks++) {
        int k0 = ks * 32;
        bf16x8 af = *(const bf16x8*)&xrow[k0 + quad * 8];
        #pragma unroll
        for (int ct = 0; ct < 9; ct++) {
            const unsigned short* bsrc = (ct < 8) ? &wt[(ct * 16 + col) * 128]
                                                  : &wa[col * 128];
            bf16x8 bf = *(const bf16x8*)&bsrc[k0 + quad * 8];
            acc[ct] = __builtin_amdgcn_mfma_f32_16x16x32_bf16(af, bf, acc[ct], 0, 0, 0);
        }
    }

    #pragma unroll
    for (int ct = 0; ct < 8; ct++) {
        #pragma unroll
        for (int r = 0; r < 4; r++) {
            int grow = row0 + wid * 16 + quad * 4 + r;
            float v = acc[ct][r];
            float vp = __shfl_xor(v, 1);
            if (!(lane & 1) && grow < n)
                hb[(size_t)grow * 64 + ct * 8 + (col >> 1)] = pk_bf16(v, vp);
        }
    }
    #pragma unroll
    for (int r = 0; r < 4; r++) {
        int grow = row0 + wid * 16 + quad * 4 + r;
        float v = acc[8][r];
        if (grow < n) {
            if (col < 8) es[(size_t)grow * 8 + col] = v;
            else         ed[(size_t)grow * 8 + col - 8] = v;
        }
    }
}

// ---------- aggregation (layers 0..L-2): packed-bf16 hA output ----------
__global__ __launch_bounds__(256) void k_aggregate(
    const unsigned int* __restrict__ hb,
    const float* __restrict__ es, const float* __restrict__ ed,
    const int* __restrict__ rowptr, const int* __restrict__ adj,
    const void* __restrict__ bias, long b_off, unsigned int* __restrict__ out,
    int n, const int* __restrict__ flags)
{
    __shared__ __align__(16) float alds[4][72 * 12];
    __shared__ __align__(16) int   slds[4][80];
    int isf32 = flags[0];
    int lane = threadIdx.x & 63;
    int wid = threadIdx.x >> 6;
    int node = blockIdx.x * 4 + wid;
    if (node >= n) return;
    int base = rowptr[node];
    int deg = rowptr[node + 1] - base;
    int head = lane >> 3;

    if (lane < 8) {
        *(float4*)&alds[wid][(64 + lane) * 12]     = make_float4(0.f, 0.f, 0.f, 0.f);
        *(float4*)&alds[wid][(64 + lane) * 12 + 4] = make_float4(0.f, 0.f, 0.f, 0.f);
        slds[wid][64 + lane] = 0;
    }

    const float4* es4 = (const float4*)es;
    const float4* ed4 = (const float4*)ed;
    float edv[8];
    {
        float4 a = ed4[node * 2];
        float4 b = ed4[node * 2 + 1];
        edv[0] = a.x; edv[1] = a.y; edv[2] = a.z; edv[3] = a.w;
        edv[4] = b.x; edv[5] = b.y; edv[6] = b.z; edv[7] = b.w;
    }

    float acc0 = 0.f, acc1 = 0.f, lsum = 0.f;
    for (int j0 = 0; j0 < deg; j0 += 64) {
        int j = j0 + lane;
        int sp = (j < deg) ? adj[base + j] : 0;
        float4 ea = es4[sp * 2];
        float4 eb = es4[sp * 2 + 1];
        float ev[8] = {ea.x, ea.y, ea.z, ea.w, eb.x, eb.y, eb.z, eb.w};
        float p[8];
        #pragma unroll
        for (int hh = 0; hh < 8; hh++) {
            float v = ev[hh] + edv[hh];
            v = fmaxf(v, 0.2f * v);
            float pe = __expf(v);
            p[hh] = (j < deg) ? pe : 0.f;
        }
        *(float4*)&alds[wid][lane * 12]     = make_float4(p[0], p[1], p[2], p[3]);
        *(float4*)&alds[wid][lane * 12 + 4] = make_float4(p[4], p[5], p[6], p[7]);
        slds[wid][lane] = sp;
        __builtin_amdgcn_s_waitcnt(0xC07F);    // lgkm(0) only

        int lim = min(64, deg - j0);
        for (int jj = 0; jj < lim; jj += 8) {
            int4 sA = *(const int4*)&slds[wid][jj];
            int4 sB = *(const int4*)&slds[wid][jj + 4];
            float a0 = alds[wid][(jj + 0) * 12 + head];
            float a1 = alds[wid][(jj + 1) * 12 + head];
            float a2 = alds[wid][(jj + 2) * 12 + head];
            float a3 = alds[wid][(jj + 3) * 12 + head];
            float a4 = alds[wid][(jj + 4) * 12 + head];
            float a5 = alds[wid][(jj + 5) * 12 + head];
            float a6 = alds[wid][(jj + 6) * 12 + head];
            float a7 = alds[wid][(jj + 7) * 12 + head];
            unsigned int h0 = hb[sA.x * 64 + lane];
            unsigned int h1 = hb[sA.y * 64 + lane];
            unsigned int h2 = hb[sA.z * 64 + lane];
            unsigned int h3 = hb[sA.w * 64 + lane];
            unsigned int h4 = hb[sB.x * 64 + lane];
            unsigned int h5 = hb[sB.y * 64 + lane];
            unsigned int h6 = hb[sB.z * 64 + lane];
            unsigned int h7 = hb[sB.w * 64 + lane];
            lsum += ((a0 + a1) + (a2 + a3)) + ((a4 + a5) + (a6 + a7));
            acc0 += a0 * bflo2f(h0) + a1 * bflo2f(h1) + a2 * bflo2f(h2) + a3 * bflo2f(h3);
            acc0 += a4 * bflo2f(h4) + a5 * bflo2f(h5) + a6 * bflo2f(h6) + a7 * bflo2f(h7);
            acc1 += a0 * bfhi2f(h0) + a1 * bfhi2f(h1) + a2 * bfhi2f(h2) + a3 * bfhi2f(h3);
            acc1 += a4 * bfhi2f(h4) + a5 * bfhi2f(h5) + a6 * bfhi2f(h6) + a7 * bfhi2f(h7);
        }
    }

    float inv = 1.f / (lsum + 1e-16f);
    int ch = lane << 1;
    float o0 = acc0 * inv + ldf(bias, b_off + ch, isf32);
    float o1 = acc1 * inv + ldf(bias, b_off + ch + 1, isf32);
    o0 = o0 > 0.f ? o0 : (__expf(o0) - 1.f);   // ELU
    o1 = o1 > 0.f ? o1 : (__expf(o1) - 1.f);
    out[(size_t)node * 64 + lane] = pk_bf16(o0, o1);
}

// ---------- final-layer aggregation with fused FC epilogue ----------
// fc_w rows are loaded AFTER the edge loop, with a loop-result-dependent
// address guard so LICM cannot hoist them (R13's 32 live VGPRs across the
// loop serialized the gathers).
__global__ __launch_bounds__(256) void k_aggregate_fc(
    const unsigned int* __restrict__ hb,
    const float* __restrict__ es, const float* __restrict__ ed,
    const int* __restrict__ rowptr, const int* __restrict__ adj,
    const void* __restrict__ bias, long b_off,
    const void* __restrict__ fw, const void* __restrict__ fb,
    void* __restrict__ out, int n, const int* __restrict__ flags)
{
    __shared__ __align__(16) float alds[4][72 * 12];
    __shared__ __align__(16) int   slds[4][80];
    int isf32 = flags[0];
    int t = threadIdx.x;
    int lane = t & 63;
    int wid = t >> 6;
    int node = blockIdx.x * 4 + wid;
    int ch = lane << 1;

    if (node >= n) return;
    int base = rowptr[node];
    int deg = rowptr[node + 1] - base;
    int head = lane >> 3;

    if (lane < 8) {
        *(float4*)&alds[wid][(64 + lane) * 12]     = make_float4(0.f, 0.f, 0.f, 0.f);
        *(float4*)&alds[wid][(64 + lane) * 12 + 4] = make_float4(0.f, 0.f, 0.f, 0.f);
        slds[wid][64 + lane] = 0;
    }

    const float4* es4 = (const float4*)es;
    const float4* ed4 = (const float4*)ed;
    float edv[8];
    {
        float4 a = ed4[node * 2];
        float4 b = ed4[node * 2 + 1];
        edv[0] = a.x; edv[1] = a.y; edv[2] = a.z; edv[3] = a.w;
        edv[4] = b.x; edv[5] = b.y; edv[6] = b.z; edv[7] = b.w;
    }

    float acc0 = 0.f, acc1 = 0.f, lsum = 0.f;
    for (int j0 = 0; j0 < deg; j0 += 64) {
        int j = j0 + lane;
        int sp = (j < deg) ? adj[base + j] : 0;
        float4 ea = es4[sp * 2];
        float4 eb = es4[sp * 2 + 1];
        float ev[8] = {ea.x, ea.y, ea.z, ea.w, eb.x, eb.y, eb.z, eb.w};
        float p[8];
        #pragma unroll
        for (int hh = 0; hh < 8; hh++) {
            float v = ev[hh] + edv[hh];
            v = fmaxf(v, 0.2f * v);
            float pe = __expf(v);
            p[hh] = (j < deg) ? pe : 0.f;
        }
        *(float4*)&alds[wid][lane * 12]     = make_float4(p[0], p[1], p[2], p[3]);
        *(float4*)&alds[wid][lane * 12 + 4] = make_float4(p[4], p[5], p[6], p[7]);
        slds[wid][lane] = sp;
        __builtin_amdgcn_s_waitcnt(0xC07F);

        int lim = min(64, deg - j0);
        for (int jj = 0; jj < lim; jj += 8) {
            int4 sA = *(const int4*)&slds[wid][jj];
            int4 sB = *(const int4*)&slds[wid][jj + 4];
            float a0 = alds[wid][(jj + 0) * 12 + head];
            float a1 = alds[wid][(jj + 1) * 12 + head];
            float a2 = alds[wid][(jj + 2) * 12 + head];
            float a3 = alds[wid][(jj + 3) * 12 + head];
            float a4 = alds[wid][(jj + 4) * 12 + head];
            float a5 = alds[wid][(jj + 5) * 12 + head];
            float a6 = alds[wid][(jj + 6) * 12 + head];
            float a7 = alds[wid][(jj + 7) * 12 + head];
            unsigned int h0 = hb[sA.x * 64 + lane];
            unsigned int h1 = hb[sA.y * 64 + lane];
            unsigned int h2 = hb[sA.z * 64 + lane];
            unsigned int h3 = hb[sA.w * 64 + lane];
            unsigned int h4 = hb[sB.x * 64 + lane];
            unsigned int h5 = hb[sB.y * 64 + lane];
            unsigned int h6 = hb[sB.z * 64 + lane];
            unsigned int h7 = hb[sB.w * 64 + lane];
            lsum += ((a0 + a1) + (a2 + a3)) + ((a4 + a5) + (a6 + a7));
            acc0 += a0 * bflo2f(h0) + a1 * bflo2f(h1) + a2 * bflo2f(h2) + a3 * bflo2f(h3);
            acc0 += a4 * bflo2f(h4) + a5 * bflo2f(h5) + a6 * bflo2f(h6) + a7 * bflo2f(h7);
            acc1 += a0 * bfhi2f(h0) + a1 * bfhi2f(h1) + a2 * bfhi2f(h2) + a3 * bfhi2f(h3);
            acc1 += a4 * bfhi2f(h4) + a5 * bfhi2f(h5) + a6 * bfhi2f(h6) + a7 * bfhi2f(h7);
        }
    }

    float inv = 1.f / (lsum + 1e-16f);
    float o0 = acc0 * inv + ldf(bias, b_off + ch, isf32);
    float o1 = acc1 * inv + ldf(bias, b_off + ch + 1, isf32);
    o0 = o0 > 0.f ? o0 : (__expf(o0) - 1.f);   // ELU
    o1 = o1 > 0.f ? o1 : (__expf(o1) - 1.f);

    // guard is provably-unknowable 0 (lsum > 0 always: self-loop => deg >= 1)
    // -> fc_w loads cannot be hoisted above the edge loop.
    int guard = (lsum > 0.f) ? 0 : 1;

    // FC epilogue: load this lane's two fc_w rows NOW (L1/L2-hot 8KB table),
    // 32 FMA, butterfly-reduce 16 outputs.
    float part[16];
    #pragma unroll
    for (int c = 0; c < 16; c++) {
        float w0 = ldf(fw, (size_t)(guard + ch * 16 + c), isf32);
        float w1 = ldf(fw, (size_t)(guard + (ch + 1) * 16 + c), isf32);
        part[c] = o0 * w0 + o1 * w1;
    }
    #pragma unroll
    for (int c = 0; c < 16; c++) {
        float r = part[c];
        #pragma unroll
        for (int off = 1; off < 64; off <<= 1) r += __shfl_xor(r, off);
        part[c] = r;
    }
    if (lane == 0) {
        if (isf32) {
            float* o = (float*)out + (size_t)node * GAT_C;
            #pragma unroll
            for (int c = 0; c < 16; c++) o[c] = part[c] + ldf(fb, c, 1);
        } else {
            __hip_bfloat16* o = (__hip_bfloat16*)out + (size_t)node * GAT_C;
            #pragma unroll
            for (int c = 0; c < 16; c++)
                o[c] = __float2bfloat16(part[c] + ldf(fb, c, 0));
        }
    }
}

extern "C" void kernel_launch(void* const* d_in, const int* in_sizes, int n_in,
                              void* d_out, int out_size, void* d_ws, size_t ws_size,
                              hipStream_t stream) {
    const void* x      = d_in[0];
    const void* Ws     = d_in[1];
    const void* att_s  = d_in[2];
    const void* att_d  = d_in[3];
    const void* biases = d_in[4];
    const void* fc_w   = d_in[5];
    const void* fc_b   = d_in[6];
    const int*  ei     = (const int*)d_in[7];

    const int N  = in_sizes[0] / GAT_F;
    const int E  = in_sizes[7] / 2;
    const int L  = in_sizes[1] / (GAT_F * GAT_F);
    const int ET = E + N;

    char* w = (char*)d_ws;
    int* flags         = (int*)w;            w += 64;
    unsigned int* hA   = (unsigned int*)w;   w += (size_t)N * 64 * 4;
    unsigned int* hB   = (unsigned int*)w;   w += (size_t)N * 64 * 4;
    float* es          = (float*)w;          w += (size_t)N * GAT_H * 4;
    float* ed          = (float*)w;          w += (size_t)N * GAT_H * 4;
    int* rowptr        = (int*)w;            w += (((size_t)(N + 1) * 4 + 15) & ~15ull);
    int* cursor        = (int*)w;            w += (size_t)N * 4;
    int* bsum          = (int*)w;            w += 1024 * 4;
    int* adj           = (int*)w;            w += (size_t)(ET + 16) * 4;
    unsigned short* wt = (unsigned short*)w; w += (size_t)L * 16384 * 2;
    unsigned short* wa = (unsigned short*)w; w += (size_t)L * 2048 * 2;

    int nb_n = (N + 255) / 256;
    int nb_e = (E + 255) / 256;
    int nb_s = (N + 1023) / 1024;
    int nb_g = (N + 63) / 64;
    int nb_a = (N + 3) / 4;

    k_detect_init<<<nb_n + 1, 256, 0, stream>>>(
        (const unsigned short*)x, ei, flags, cursor, N, nb_n);
    k_prep_count<<<L * 72 + nb_e, 256, 0, stream>>>(
        Ws, att_s, att_d, wt, wa, L, ei, cursor, E, flags);
    k_scan_blk<<<nb_s, 256, 0, stream>>>(cursor, rowptr, bsum, N);
    k_place_add<<<nb_n, 256, 0, stream>>>(rowptr, bsum, adj, cursor, N, nb_s);

    // fused: gemm layer 0 + scatter
    k_gemm_scatter<<<nb_g + nb_e, 256, 0, stream>>>(
        x, wt, wa, hB, es, ed, N, nb_g,
        ei, rowptr, cursor, adj, E, flags);

    for (int l = 0; l < L; l++) {
        if (l > 0) {
            k_gemm_mfma<<<nb_g, 256, 0, stream>>>(
                hA, wt + (size_t)l * 16384, wa + (size_t)l * 2048,
                hB, es, ed, N, flags);
        }
        if (l < L - 1) {
            k_aggregate<<<nb_a, 256, 0, stream>>>(
                hB, es, ed, rowptr, adj,
                biases, (long)l * GAT_F, hA, N, flags);
        } else {
            k_aggregate_fc<<<nb_a, 256, 0, stream>>>(
                hB, es, ed, rowptr, adj,
                biases, (long)l * GAT_F, fc_w, fc_b, d_out, N, flags);
        }
    }
}

// Round 15
// 384.790 us; speedup vs baseline: 1.3607x; 1.3607x over previous
//
#include <hip/hip_runtime.h>
#include <hip/hip_bf16.h>

// GAT: N=50000 nodes, E=800000 edges, L=3 layers, H=8 heads, C=16, F=128.
// flags[0]=1 -> float tensors fp32 (else bf16); flags[1]=1 -> edge_index int64.
// R15 = R11 verbatim (best measured: 389.8us). R12-R14 post-mortem: fusing FC
// into the last aggregate lost 2-4x through three mechanisms (LDS bank
// conflicts at stride-128B; then scheduling/MLP loss from the 96-shfl
// butterfly epilogue regardless of fw placement). Unfused k_fc (~8us) wins.
// Proven floors: scatter ~54us (64B write-allocate per 4B store; 2 restructures
// regressed), aggregate ~50us/layer (256B/edge gather + VALU), gemm_l0 hidden
// inside scatter's stall window (MfmaUtil 1.1% there).

#define GAT_F 128
#define GAT_H 8
#define GAT_C 16

typedef __attribute__((ext_vector_type(8))) short bf16x8;
typedef __attribute__((ext_vector_type(4))) float f32x4;

__device__ __forceinline__ float bf2f(unsigned short u) {
    union { unsigned int i; float f; } x; x.i = ((unsigned int)u) << 16; return x.f;
}
__device__ __forceinline__ float bfhi2f(unsigned int u) {
    union { unsigned int i; float f; } x; x.i = u & 0xFFFF0000u; return x.f;
}
__device__ __forceinline__ float bflo2f(unsigned int u) {
    union { unsigned int i; float f; } x; x.i = u << 16; return x.f;
}
__device__ __forceinline__ unsigned int pk_bf16(float a, float b) {  // rne pack
    union { float f; unsigned int i; } ua, ub;
    ua.f = a; ub.f = b;
    unsigned int ra = (ua.i + 0x7FFFu + ((ua.i >> 16) & 1u)) >> 16;
    unsigned int rb = (ub.i + 0x7FFFu + ((ub.i >> 16) & 1u)) & 0xFFFF0000u;
    return ra | rb;
}
__device__ __forceinline__ unsigned short f2bf(float a) {
    union { float f; unsigned int i; } ua; ua.f = a;
    return (unsigned short)((ua.i + 0x7FFFu + ((ua.i >> 16) & 1u)) >> 16);
}
__device__ __forceinline__ float ldf(const void* p, size_t i, int isf32) {
    return isf32 ? ((const float*)p)[i] : bf2f(((const unsigned short*)p)[i]);
}
__device__ __forceinline__ int ldei(const int* ei, int i, int is64) {
    return is64 ? ei[2 * (size_t)i] : ei[i];
}

// ---------- fused: dtype detection (last block) + init_deg (others) ----------
__global__ void k_detect_init(const unsigned short* __restrict__ xb,
                              const int* __restrict__ ei, int* flags,
                              int* deg, int n, int nb_n) {
    if ((int)blockIdx.x < nb_n) {
        int i = blockIdx.x * 256 + threadIdx.x;
        if (i < n) deg[i] = 1;  // self loop
        return;
    }
    __shared__ int nan_cnt, zero_cnt;
    if (threadIdx.x == 0) { nan_cnt = 0; zero_cnt = 0; }
    __syncthreads();
    int t = threadIdx.x;
    int ln = 0;
    for (int i = t; i < 8192; i += 256) {
        unsigned short u = xb[i];
        if ((u & 0x7F80) == 0x7F80) ln++;   // bf16 inf/nan pattern
    }
    int lz = 0;
    for (int i = t; i < 2048; i += 256) {
        if (ei[2 * i + 1] == 0) lz++;       // int64 high words all zero
    }
    if (ln) atomicAdd(&nan_cnt, ln);
    if (lz) atomicAdd(&zero_cnt, lz);
    __syncthreads();
    if (t == 0) {
        flags[0] = (nan_cnt > 3) ? 1 : 0;
        flags[1] = (zero_cnt > 1024) ? 1 : 0;
    }
}

// ---------- fused: prep (first Lw*72 blocks) + count_deg (rest) ----------
__global__ void k_prep_count(const void* __restrict__ W, const void* __restrict__ asrc,
                             const void* __restrict__ adst,
                             unsigned short* __restrict__ wt, unsigned short* __restrict__ wa,
                             int Lw, const int* __restrict__ ei, int* deg, int E,
                             const int* __restrict__ flags) {
    int isf32 = flags[0];
    int b = blockIdx.x, t = threadIdx.x;
    if (b < Lw * 64) {
        int gid = b * 256 + t;                 // over L*16384
        int l = gid >> 14, r = gid & 16383;
        int c = r >> 7, k = r & 127;
        float v = ldf(W, (size_t)l * 16384 + k * 128 + c, isf32);
        wt[gid] = f2bf(v);                     // wt layout: l*16384 + c*128 + k
    } else if (b < Lw * 72) {
        int id = (b - Lw * 64) * 256 + t;      // over L*2048
        int l = id >> 11, q = id & 2047;
        int j = q >> 7, k = q & 127;
        int head = j & 7;
        const void* av = (j < 8) ? asrc : adst;
        float acc = 0.f;
        #pragma unroll
        for (int cc = 0; cc < 16; cc++) {
            float w = ldf(W, (size_t)l * 16384 + k * 128 + head * 16 + cc, isf32);
            float a = ldf(av, (size_t)l * 128 + head * 16 + cc, isf32);
            acc += w * a;
        }
        wa[id] = f2bf(acc);                    // wa layout: l*2048 + j*128 + k
    } else {
        int k = (b - Lw * 72) * 256 + t;
        int is64 = flags[1];
        if (k < E) atomicAdd(&deg[ldei(ei, E + k, is64)], 1);
    }
}

__global__ __launch_bounds__(256) void k_scan_blk(
    const int* __restrict__ deg, int* __restrict__ rp_local,
    int* __restrict__ bsum, int n)
{
    int b = blockIdx.x, t = threadIdx.x;
    int i0 = b * 1024 + t * 4;
    int v0 = 0, v1 = 0, v2 = 0, v3 = 0;
    if (i0 + 3 < n) {
        int4 d = *(const int4*)(deg + i0);
        v0 = d.x; v1 = d.y; v2 = d.z; v3 = d.w;
    } else {
        if (i0     < n) v0 = deg[i0];
        if (i0 + 1 < n) v1 = deg[i0 + 1];
        if (i0 + 2 < n) v2 = deg[i0 + 2];
        if (i0 + 3 < n) v3 = deg[i0 + 3];
    }
    int s = v0 + v1 + v2 + v3;
    int lane = t & 63, wid = t >> 6;
    int sc = s;
    #pragma unroll
    for (int off = 1; off < 64; off <<= 1) {
        int o = __shfl_up(sc, off);
        if (lane >= off) sc += o;
    }
    __shared__ int wsum[4];
    if (lane == 63) wsum[wid] = sc;
    __syncthreads();
    int woff = 0;
    #pragma unroll
    for (int w2 = 0; w2 < 4; w2++) if (w2 < wid) woff += wsum[w2];
    int excl = woff + sc - s;
    if (i0     < n) rp_local[i0]     = excl;
    if (i0 + 1 < n) rp_local[i0 + 1] = excl + v0;
    if (i0 + 2 < n) rp_local[i0 + 2] = excl + v0 + v1;
    if (i0 + 3 < n) rp_local[i0 + 3] = excl + v0 + v1 + v2;
    if (t == 255) bsum[b] = woff + sc;
}

// place_add with inline scan of bsum (raw per-block totals; nb_s <= 1024)
__global__ void k_place_add(int* __restrict__ rowptr, const int* __restrict__ bsum,
                            int* __restrict__ adj, int* __restrict__ cursor,
                            int n, int nb_s)
{
    int i = blockIdx.x * 256 + threadIdx.x;
    if (i < n) {
        int myblk = i >> 10;
        int off = 0;
        for (int b = 0; b < myblk; b++) off += bsum[b];   // <=48 L1-hot loads
        int r = rowptr[i] + off;
        rowptr[i] = r;
        adj[r] = i;
        cursor[i] = 1;
    }
    if (blockIdx.x == 0 && threadIdx.x < 9) {
        int tot = 0;
        for (int b = 0; b < nb_s; b++) tot += bsum[b];
        if (threadIdx.x == 0) rowptr[n] = tot;
        else adj[tot + threadIdx.x - 1] = 0;   // pad 8 slots for agg unroll overread
    }
}

// ---------- fused: gemm layer 0 (blocks < nb_g) + scatter (rest) ----------
// Independent work: gemm_l0 reads x/wt/wa, scatter writes adj. The scatter is
// memory-stall-bound (VALU 0.9%) -> gemm's MFMA work hides inside its window.
__global__ __launch_bounds__(256) void k_gemm_scatter(
    const void* __restrict__ xin,
    const unsigned short* __restrict__ wt, const unsigned short* __restrict__ wa,
    unsigned int* __restrict__ hb, float* __restrict__ es, float* __restrict__ ed,
    int n, int nb_g,
    const int* __restrict__ ei, const int* __restrict__ rowptr,
    int* __restrict__ cursor, int* __restrict__ adj, int E,
    const int* __restrict__ flags)
{
    __shared__ unsigned short xl[64 * 136];
    int isf32 = flags[0];
    int t = threadIdx.x;

    if ((int)blockIdx.x >= nb_g) {   // ---- scatter blocks ----
        int k = ((int)blockIdx.x - nb_g) * 256 + t;
        int is64 = flags[1];
        if (k < E) {
            int s = ldei(ei, k, is64);
            int d = ldei(ei, E + k, is64);
            int p = atomicAdd(&cursor[d], 1);
            adj[rowptr[d] + p] = s;
        }
        return;
    }

    // ---- gemm layer 0 (x_is_input) ----
    int row0 = blockIdx.x * 64;
    int lane = t & 63, wid = t >> 6, quad = lane >> 4, col = lane & 15;

    bool direct = !isf32;   // bf16 input tensor -> read fragments from global
    if (!direct) {
        const float4* xg = (const float4*)xin;
        for (int i = t; i < 2048; i += 256) {
            int r = i >> 5, c4 = i & 31;
            int gr = row0 + r;
            uint2 u = make_uint2(0u, 0u);
            if (gr < n) {
                float4 v = xg[(size_t)gr * 32 + c4];
                u = make_uint2(pk_bf16(v.x, v.y), pk_bf16(v.z, v.w));
            }
            *(uint2*)&xl[r * 136 + c4 * 4] = u;
        }
        __syncthreads();
    }

    int arow = row0 + wid * 16 + col;
    int arowc = min(arow, n - 1);
    const unsigned short* xrow = direct
        ? ((const unsigned short*)xin + (size_t)arowc * 128)
        : &xl[(wid * 16 + col) * 136];

    f32x4 acc[9];
    #pragma unroll
    for (int ct = 0; ct < 9; ct++) acc[ct] = (f32x4){0.f, 0.f, 0.f, 0.f};

    #pragma unroll
    for (int ks = 0; ks < 4; ks++) {
        int k0 = ks * 32;
        bf16x8 af = *(const bf16x8*)&xrow[k0 + quad * 8];
        #pragma unroll
        for (int ct = 0; ct < 9; ct++) {
            const unsigned short* bsrc = (ct < 8) ? &wt[(ct * 16 + col) * 128]
                                                  : &wa[col * 128];
            bf16x8 bf = *(const bf16x8*)&bsrc[k0 + quad * 8];
            acc[ct] = __builtin_amdgcn_mfma_f32_16x16x32_bf16(af, bf, acc[ct], 0, 0, 0);
        }
    }

    #pragma unroll
    for (int ct = 0; ct < 8; ct++) {
        #pragma unroll
        for (int r = 0; r < 4; r++) {
            int grow = row0 + wid * 16 + quad * 4 + r;
            float v = acc[ct][r];
            float vp = __shfl_xor(v, 1);
            if (!(lane & 1) && grow < n)
                hb[(size_t)grow * 64 + ct * 8 + (col >> 1)] = pk_bf16(v, vp);
        }
    }
    #pragma unroll
    for (int r = 0; r < 4; r++) {
        int grow = row0 + wid * 16 + quad * 4 + r;
        float v = acc[8][r];
        if (grow < n) {
            if (col < 8) es[(size_t)grow * 8 + col] = v;
            else         ed[(size_t)grow * 8 + col - 8] = v;
        }
    }
}

// ---------- MFMA GEMM (layers 1..L-1, packed-bf16 input) ----------
__global__ __launch_bounds__(256) void k_gemm_mfma(
    const void* __restrict__ xin,
    const unsigned short* __restrict__ wt, const unsigned short* __restrict__ wa,
    unsigned int* __restrict__ hb, float* __restrict__ es, float* __restrict__ ed,
    int n, const int* __restrict__ flags)
{
    int t = threadIdx.x;
    int row0 = blockIdx.x * 64;
    int lane = t & 63, wid = t >> 6, quad = lane >> 4, col = lane & 15;

    int arow = row0 + wid * 16 + col;
    int arowc = min(arow, n - 1);
    const unsigned short* xrow = (const unsigned short*)xin + (size_t)arowc * 128;

    f32x4 acc[9];
    #pragma unroll
    for (int ct = 0; ct < 9; ct++) acc[ct] = (f32x4){0.f, 0.f, 0.f, 0.f};

    #pragma unroll
    for (int ks = 0; ks < 4; ks++) {
        int k0 = ks * 32;
        bf16x8 af = *(const bf16x8*)&xrow[k0 + quad * 8];
        #pragma unroll
        for (int ct = 0; ct < 9; ct++) {
            const unsigned short* bsrc = (ct < 8) ? &wt[(ct * 16 + col) * 128]
                                                  : &wa[col * 128];
            bf16x8 bf = *(const bf16x8*)&bsrc[k0 + quad * 8];
            acc[ct] = __builtin_amdgcn_mfma_f32_16x16x32_bf16(af, bf, acc[ct], 0, 0, 0);
        }
    }

    #pragma unroll
    for (int ct = 0; ct < 8; ct++) {
        #pragma unroll
        for (int r = 0; r < 4; r++) {
            int grow = row0 + wid * 16 + quad * 4 + r;
            float v = acc[ct][r];
            float vp = __shfl_xor(v, 1);
            if (!(lane & 1) && grow < n)
                hb[(size_t)grow * 64 + ct * 8 + (col >> 1)] = pk_bf16(v, vp);
        }
    }
    #pragma unroll
    for (int r = 0; r < 4; r++) {
        int grow = row0 + wid * 16 + quad * 4 + r;
        float v = acc[8][r];
        if (grow < n) {
            if (col < 8) es[(size_t)grow * 8 + col] = v;
            else         ed[(size_t)grow * 8 + col - 8] = v;
        }
    }
}

// ---------- aggregation: one wave per node, two-phase LDS-alpha, 8x unroll ----------
__global__ __launch_bounds__(256) void k_aggregate(
    const unsigned int* __restrict__ hb,   // packed bf16x2, stride 64 dwords
    const float* __restrict__ es, const float* __restrict__ ed,
    const int* __restrict__ rowptr, const int* __restrict__ adj,
    const void* __restrict__ bias, long b_off, unsigned int* __restrict__ out,
    int n, const int* __restrict__ flags)
{
    __shared__ __align__(16) float alds[4][72 * 12];   // alpha[edge][head], stride 12
    __shared__ __align__(16) int   slds[4][80];        // src ids (72 used)
    int isf32 = flags[0];
    int lane = threadIdx.x & 63;
    int wid = threadIdx.x >> 6;
    int node = blockIdx.x * 4 + wid;
    if (node >= n) return;
    int base = rowptr[node];
    int deg = rowptr[node + 1] - base;
    int head = lane >> 3;

    if (lane < 8) {
        *(float4*)&alds[wid][(64 + lane) * 12]     = make_float4(0.f, 0.f, 0.f, 0.f);
        *(float4*)&alds[wid][(64 + lane) * 12 + 4] = make_float4(0.f, 0.f, 0.f, 0.f);
        slds[wid][64 + lane] = 0;
    }

    const float4* es4 = (const float4*)es;
    const float4* ed4 = (const float4*)ed;
    float edv[8];
    {
        float4 a = ed4[node * 2];
        float4 b = ed4[node * 2 + 1];
        edv[0] = a.x; edv[1] = a.y; edv[2] = a.z; edv[3] = a.w;
        edv[4] = b.x; edv[5] = b.y; edv[6] = b.z; edv[7] = b.w;
    }

    float acc0 = 0.f, acc1 = 0.f, lsum = 0.f;
    for (int j0 = 0; j0 < deg; j0 += 64) {
        int j = j0 + lane;
        int sp = (j < deg) ? adj[base + j] : 0;
        float4 ea = es4[sp * 2];
        float4 eb = es4[sp * 2 + 1];
        float ev[8] = {ea.x, ea.y, ea.z, ea.w, eb.x, eb.y, eb.z, eb.w};
        float p[8];
        #pragma unroll
        for (int hh = 0; hh < 8; hh++) {
            float v = ev[hh] + edv[hh];
            v = fmaxf(v, 0.2f * v);            // leaky relu
            float pe = __expf(v);              // bounded scores: no overflow
            p[hh] = (j < deg) ? pe : 0.f;
        }
        *(float4*)&alds[wid][lane * 12]     = make_float4(p[0], p[1], p[2], p[3]);
        *(float4*)&alds[wid][lane * 12 + 4] = make_float4(p[4], p[5], p[6], p[7]);
        slds[wid][lane] = sp;
        __builtin_amdgcn_s_waitcnt(0xC07F);    // lgkm(0) only — keep vm loads in flight

        int lim = min(64, deg - j0);
        for (int jj = 0; jj < lim; jj += 8) {
            int4 sA = *(const int4*)&slds[wid][jj];
            int4 sB = *(const int4*)&slds[wid][jj + 4];
            float a0 = alds[wid][(jj + 0) * 12 + head];
            float a1 = alds[wid][(jj + 1) * 12 + head];
            float a2 = alds[wid][(jj + 2) * 12 + head];
            float a3 = alds[wid][(jj + 3) * 12 + head];
            float a4 = alds[wid][(jj + 4) * 12 + head];
            float a5 = alds[wid][(jj + 5) * 12 + head];
            float a6 = alds[wid][(jj + 6) * 12 + head];
            float a7 = alds[wid][(jj + 7) * 12 + head];
            unsigned int h0 = hb[sA.x * 64 + lane];
            unsigned int h1 = hb[sA.y * 64 + lane];
            unsigned int h2 = hb[sA.z * 64 + lane];
            unsigned int h3 = hb[sA.w * 64 + lane];
            unsigned int h4 = hb[sB.x * 64 + lane];
            unsigned int h5 = hb[sB.y * 64 + lane];
            unsigned int h6 = hb[sB.z * 64 + lane];
            unsigned int h7 = hb[sB.w * 64 + lane];
            lsum += ((a0 + a1) + (a2 + a3)) + ((a4 + a5) + (a6 + a7));
            acc0 += a0 * bflo2f(h0) + a1 * bflo2f(h1) + a2 * bflo2f(h2) + a3 * bflo2f(h3);
            acc0 += a4 * bflo2f(h4) + a5 * bflo2f(h5) + a6 * bflo2f(h6) + a7 * bflo2f(h7);
            acc1 += a0 * bfhi2f(h0) + a1 * bfhi2f(h1) + a2 * bfhi2f(h2) + a3 * bfhi2f(h3);
            acc1 += a4 * bfhi2f(h4) + a5 * bfhi2f(h5) + a6 * bfhi2f(h6) + a7 * bfhi2f(h7);
        }
    }

    float inv = 1.f / (lsum + 1e-16f);
    int ch = lane << 1;
    float o0 = acc0 * inv + ldf(bias, b_off + ch, isf32);
    float o1 = acc1 * inv + ldf(bias, b_off + ch + 1, isf32);
    o0 = o0 > 0.f ? o0 : (__expf(o0) - 1.f);   // ELU
    o1 = o1 > 0.f ? o1 : (__expf(o1) - 1.f);
    out[(size_t)node * 64 + lane] = pk_bf16(o0, o1);
}

// ---------- final FC: packed-bf16 input [n,64 dwords] @ [128,16] + b ----------
__global__ __launch_bounds__(256) void k_fc(
    const unsigned int* __restrict__ h, const void* __restrict__ fw,
    const void* __restrict__ fb, void* __restrict__ out, int n,
    const int* __restrict__ flags)
{
    __shared__ float fws[GAT_F * GAT_C];
    int isf32 = flags[0];
    int t = threadIdx.x;
    for (int i = t; i < GAT_F * GAT_C; i += 256)
        fws[i] = ldf(fw, i, isf32);
    __syncthreads();
    int row = blockIdx.x * 256 + t;
    if (row >= n) return;
    float acc[16];
    #pragma unroll
    for (int c = 0; c < 16; c++) acc[c] = ldf(fb, c, isf32);
    const unsigned int* hr = h + (size_t)row * 64;
    for (int k2 = 0; k2 < 64; k2++) {
        unsigned int u = hr[k2];
        float x0 = bflo2f(u), x1 = bfhi2f(u);
        const float4* w0 = (const float4*)&fws[(2 * k2) * 16];
        const float4* w1 = (const float4*)&fws[(2 * k2 + 1) * 16];
        #pragma unroll
        for (int c4 = 0; c4 < 4; c4++) {
            float4 wv0 = w0[c4], wv1 = w1[c4];
            acc[c4 * 4 + 0] += x0 * wv0.x + x1 * wv1.x;
            acc[c4 * 4 + 1] += x0 * wv0.y + x1 * wv1.y;
            acc[c4 * 4 + 2] += x0 * wv0.z + x1 * wv1.z;
            acc[c4 * 4 + 3] += x0 * wv0.w + x1 * wv1.w;
        }
    }
    if (isf32) {
        float* o = (float*)out + (size_t)row * GAT_C;
        #pragma unroll
        for (int c = 0; c < 16; c++) o[c] = acc[c];
    } else {
        __hip_bfloat16* o = (__hip_bfloat16*)out + (size_t)row * GAT_C;
        #pragma unroll
        for (int c = 0; c < 16; c++) o[c] = __float2bfloat16(acc[c]);
    }
}

extern "C" void kernel_launch(void* const* d_in, const int* in_sizes, int n_in,
                              void* d_out, int out_size, void* d_ws, size_t ws_size,
                              hipStream_t stream) {
    const void* x      = d_in[0];
    const void* Ws     = d_in[1];
    const void* att_s  = d_in[2];
    const void* att_d  = d_in[3];
    const void* biases = d_in[4];
    const void* fc_w   = d_in[5];
    const void* fc_b   = d_in[6];
    const int*  ei     = (const int*)d_in[7];

    const int N  = in_sizes[0] / GAT_F;
    const int E  = in_sizes[7] / 2;
    const int L  = in_sizes[1] / (GAT_F * GAT_F);
    const int ET = E + N;

    char* w = (char*)d_ws;
    int* flags         = (int*)w;            w += 64;
    unsigned int* hA   = (unsigned int*)w;   w += (size_t)N * 64 * 4;   // packed bf16 agg out
    unsigned int* hB   = (unsigned int*)w;   w += (size_t)N * 64 * 4;   // packed bf16 gemm out
    float* es          = (float*)w;          w += (size_t)N * GAT_H * 4;
    float* ed          = (float*)w;          w += (size_t)N * GAT_H * 4;
    int* rowptr        = (int*)w;            w += (((size_t)(N + 1) * 4 + 15) & ~15ull);
    int* cursor        = (int*)w;            w += (size_t)N * 4;
    int* bsum          = (int*)w;            w += 1024 * 4;
    int* adj           = (int*)w;            w += (size_t)(ET + 16) * 4;
    unsigned short* wt = (unsigned short*)w; w += (size_t)L * 16384 * 2;
    unsigned short* wa = (unsigned short*)w; w += (size_t)L * 2048 * 2;

    int nb_n = (N + 255) / 256;
    int nb_e = (E + 255) / 256;
    int nb_s = (N + 1023) / 1024;
    int nb_g = (N + 63) / 64;
    int nb_a = (N + 3) / 4;

    k_detect_init<<<nb_n + 1, 256, 0, stream>>>(
        (const unsigned short*)x, ei, flags, cursor, N, nb_n);
    k_prep_count<<<L * 72 + nb_e, 256, 0, stream>>>(
        Ws, att_s, att_d, wt, wa, L, ei, cursor, E, flags);
    k_scan_blk<<<nb_s, 256, 0, stream>>>(cursor, rowptr, bsum, N);
    k_place_add<<<nb_n, 256, 0, stream>>>(rowptr, bsum, adj, cursor, N, nb_s);

    // fused: gemm layer 0 + scatter (independent; scatter's stall hides gemm)
    k_gemm_scatter<<<nb_g + nb_e, 256, 0, stream>>>(
        x, wt, wa, hB, es, ed, N, nb_g,
        ei, rowptr, cursor, adj, E, flags);
    k_aggregate<<<nb_a, 256, 0, stream>>>(
        hB, es, ed, rowptr, adj, biases, 0L, hA, N, flags);

    for (int l = 1; l < L; l++) {
        k_gemm_mfma<<<nb_g, 256, 0, stream>>>(
            hA, wt + (size_t)l * 16384, wa + (size_t)l * 2048,
            hB, es, ed, N, flags);
        k_aggregate<<<nb_a, 256, 0, stream>>>(
            hB, es, ed, rowptr, adj,
            biases, (long)l * GAT_F, hA, N, flags);
    }
    k_fc<<<nb_n, 256, 0, stream>>>(hA, fc_w, fc_b, d_out, N, flags);
}